// Round 4
// baseline (189.095 us; speedup 1.0000x reference)
//
#include <hip/hip_runtime.h>

#define NTAG 64
#define TLEN 512
#define START_TAG 62
#define STOP_TAG 63
#define CHUNK 32          // timesteps staged per LDS buffer
#define HALF (TLEN / 2)   // 256 steps per direction

__device__ __forceinline__ float bcast_lane(float v, int k) {
    return __uint_as_float(__builtin_amdgcn_readlane(__float_as_uint(v), k));
}

// One workgroup (128 threads = 2 waves) per batch element.
//   wave 0: forward  a_{t+1}[n] = (sum_p E[n,p] a_t[p]) * w_t[n],  t=0..255
//   wave 1: backward b_t[p]     =  sum_n E[n,p] (w_t[n] b_{t+1}[n]), t=511..256
// E = exp(trans) constant in VGPRs; w_t = exp(emis_t) precomputed into LDS
// at staging time. Linear domain — no exp/log in the recurrence.
// Exact power-of-2 renorm every 4 steps bounds dynamic range.
//
// Round-4 change vs round 3: the step loop is NO LONGER fully unrolled.
// Round 3's 32-step unroll made the hot body ~35 KB/direction (~70 KB total),
// blowing past the 32 KB L1I; at 1 wave/SIMD instruction-fetch misses were
// fully exposed (~650 cyc/step of stall, VALUBusy 40%). Hot body is now
// 4 steps (~4.5 KB) and stays resident in L1I.
__global__ __launch_bounds__(128) void crf_fwd_bwd(
    const float* __restrict__ emis,   // [B, T, L]
    const float* __restrict__ trans,  // [L, L]  trans[next, prev]
    float* __restrict__ out)          // [B]
{
    const int b    = blockIdx.x;
    const int tid  = threadIdx.x;
    const int lane = tid & 63;
    const int w    = tid >> 6;  // 0 = forward, 1 = backward

    // [wave][buf][CHUNK*NTAG] : 2*2*2048 floats = 32 KB (holds exp(emis))
    __shared__ float lds[2 * 2 * CHUNK * NTAG];
    __shared__ float sh[2][NTAG];

    const float L2E = 1.4426950408889634f;
    const float LN2 = 0.6931471805599453f;

    // Per-lane transition row, exponentiated, held in 64 VGPRs.
    //   fwd: E[k] = exp(trans[lane, k])  (reduce over prev = k)
    //   bwd: E[k] = exp(trans[k, lane])  (reduce over next = k)
    // Masked entries (-10000) flush to exactly 0.
    float E[NTAG];
    if (w == 0) {
        const float4* rowp = (const float4*)(trans + lane * NTAG);
        #pragma unroll
        for (int k4 = 0; k4 < NTAG / 4; ++k4) {
            float4 v = rowp[k4];
            E[4 * k4 + 0] = exp2f(v.x * L2E);
            E[4 * k4 + 1] = exp2f(v.y * L2E);
            E[4 * k4 + 2] = exp2f(v.z * L2E);
            E[4 * k4 + 3] = exp2f(v.w * L2E);
        }
    } else {
        #pragma unroll
        for (int k = 0; k < NTAG; ++k)
            E[k] = exp2f(trans[k * NTAG + lane] * L2E);
    }

    const float* eb = emis + (size_t)b * TLEN * NTAG;

    // chunk staging: 8 float4/lane covers CHUNK*NTAG floats per chunk
    float4 r0, r1, r2, r3, r4, r5, r6, r7;
    #define LOAD_CHUNK(baseT)                                        \
        do {                                                         \
            const float4* gp = (const float4*)(eb + (baseT) * NTAG); \
            r0 = gp[0 * 64 + lane]; r1 = gp[1 * 64 + lane];          \
            r2 = gp[2 * 64 + lane]; r3 = gp[3 * 64 + lane];          \
            r4 = gp[4 * 64 + lane]; r5 = gp[5 * 64 + lane];          \
            r6 = gp[6 * 64 + lane]; r7 = gp[7 * 64 + lane];          \
        } while (0)

    // exp() applied at store time: w = exp(emis) lands in LDS; the 32
    // quarter-rate v_exp per chunk are OFF the recurrence's critical path.
    #define EXP4(v) make_float4(exp2f((v).x * L2E), exp2f((v).y * L2E), \
                                exp2f((v).z * L2E), exp2f((v).w * L2E))
    #define STORE_CHUNK_EXP(bufp)                                    \
        do {                                                         \
            float4* b4 = (float4*)(bufp);                            \
            b4[0 * 64 + lane] = EXP4(r0); b4[1 * 64 + lane] = EXP4(r1); \
            b4[2 * 64 + lane] = EXP4(r2); b4[3 * 64 + lane] = EXP4(r3); \
            b4[4 * 64 + lane] = EXP4(r4); b4[5 * 64 + lane] = EXP4(r5); \
            b4[6 * 64 + lane] = EXP4(r6); b4[7 * 64 + lane] = EXP4(r7); \
        } while (0)

    #define MATVEC(p, ssum)                                          \
        do {                                                         \
            float a0 = 0.f, a1 = 0.f, a2 = 0.f, a3 = 0.f;            \
            float a4 = 0.f, a5 = 0.f, a6 = 0.f, a7 = 0.f;            \
            _Pragma("unroll")                                        \
            for (int k = 0; k < NTAG; k += 8) {                      \
                a0 = fmaf(bcast_lane(p, k + 0), E[k + 0], a0);       \
                a1 = fmaf(bcast_lane(p, k + 1), E[k + 1], a1);       \
                a2 = fmaf(bcast_lane(p, k + 2), E[k + 2], a2);       \
                a3 = fmaf(bcast_lane(p, k + 3), E[k + 3], a3);       \
                a4 = fmaf(bcast_lane(p, k + 4), E[k + 4], a4);       \
                a5 = fmaf(bcast_lane(p, k + 5), E[k + 5], a5);       \
                a6 = fmaf(bcast_lane(p, k + 6), E[k + 6], a6);       \
                a7 = fmaf(bcast_lane(p, k + 7), E[k + 7], a7);       \
            }                                                        \
            ssum = ((a0 + a1) + (a2 + a3)) + ((a4 + a5) + (a6 + a7)); \
        } while (0)

    // exact power-of-2 renorm: scale so lane-0's exponent returns to 0.
    // lane 0 (tag 0) is never masked and is within e^12 of the max.
    #define RENORM(x, off)                                                 \
        do {                                                               \
            unsigned _bb = __builtin_amdgcn_readlane(__float_as_uint(x), 0); \
            int _e = (int)((_bb >> 23) & 0xffu) - 127;                     \
            off += _e;                                                     \
            x *= __uint_as_float((unsigned)(127 - _e) << 23);              \
        } while (0)

    float x;        // recursion state, one tag per lane
    int   off = 0;  // accumulated power-of-2 offset (exact)

    if (w == 0) {
        x = (lane == START_TAG) ? 1.0f : 0.0f;  // a_0 = exp(init)

        LOAD_CHUNK(0);
        #pragma clang loop unroll(disable)
        for (int ci = 0; ci < 8; ++ci) {
            float* buf = &lds[(ci & 1) * (CHUNK * NTAG)];
            STORE_CHUNK_EXP(buf);
            if (ci < 7) LOAD_CHUNK((ci + 1) * CHUNK);  // in flight ~32 steps

            float wcur = buf[lane];
            #pragma clang loop unroll(disable)
            for (int sg = 0; sg < 8; ++sg) {
                #pragma unroll
                for (int q = 0; q < 4; ++q) {
                    const int s  = sg * 4 + q;
                    const int sn = (s + 1 < CHUNK) ? s + 1 : s;
                    float wnext = buf[sn * NTAG + lane];  // prefetch
                    float ssum;
                    MATVEC(x, ssum);
                    x = ssum * wcur;
                    wcur = wnext;
                }
                RENORM(x, off);
            }
        }
    } else {
        x = exp2f(trans[STOP_TAG * NTAG + lane] * L2E);  // b_T = exp(trans[STOP,:])

        LOAD_CHUNK(HALF + 7 * CHUNK);
        #pragma clang loop unroll(disable)
        for (int i = 0; i < 8; ++i) {
            const int ci = 7 - i;                         // consume descending t
            float* buf = &lds[(2 + (i & 1)) * (CHUNK * NTAG)];
            STORE_CHUNK_EXP(buf);
            if (i < 7) LOAD_CHUNK(HALF + (ci - 1) * CHUNK);

            float wcur = buf[(CHUNK - 1) * NTAG + lane];
            #pragma clang loop unroll(disable)
            for (int sg = 0; sg < 8; ++sg) {
                #pragma unroll
                for (int q = 0; q < 4; ++q) {
                    const int s  = CHUNK - 1 - (sg * 4 + q);
                    const int sn = (s > 0) ? s - 1 : 0;
                    float wnext = buf[sn * NTAG + lane];  // prefetch
                    float u = x * wcur;
                    float ssum;
                    MATVEC(u, ssum);
                    x = ssum;
                    wcur = wnext;
                }
                RENORM(x, off);
            }
        }
    }

    // back to log2 domain once, merge the two half-chains
    sh[w][lane] = log2f(x) + (float)off;   // -inf for masked tags, safe
    __syncthreads();

    if (w == 0) {
        float v = sh[0][lane] + sh[1][lane];
        float m = v;
        #pragma unroll
        for (int d = 1; d < 64; d <<= 1) m = fmaxf(m, __shfl_xor(m, d, 64));
        float e = exp2f(v - m);
        #pragma unroll
        for (int d = 1; d < 64; d <<= 1) e += __shfl_xor(e, d, 64);
        if (lane == 0) out[b] = LN2 * (m + log2f(e));
    }
}

extern "C" void kernel_launch(void* const* d_in, const int* in_sizes, int n_in,
                              void* d_out, int out_size, void* d_ws, size_t ws_size,
                              hipStream_t stream) {
    const float* emis  = (const float*)d_in[0];   // [512, 512, 64] f32
    const float* trans = (const float*)d_in[1];   // [64, 64] f32
    float* out = (float*)d_out;                   // [512] f32
    (void)in_sizes; (void)n_in; (void)out_size; (void)d_ws; (void)ws_size;
    crf_fwd_bwd<<<512, 128, 0, stream>>>(emis, trans, out);
}

// Round 5
// 146.408 us; speedup vs baseline: 1.2916x; 1.2916x over previous
//
#include <hip/hip_runtime.h>

#define NTAG 64
#define TLEN 512
#define START_TAG 62
#define STOP_TAG 63
#define CHUNK 32          // timesteps staged per LDS buffer
#define HALF (TLEN / 2)   // 256 steps per direction

// One workgroup (128 threads = 2 waves) per batch element.
//   wave 0: forward  a_{t+1}[n] = (sum_p E[n,p] a_t[p]) * w_t[n],  t=0..255
//   wave 1: backward y_{t-1}[n] = w_{t-1}[n] * sum_k E[k,n] y_t[k], t=511..256
// E = exp(trans) constant in VGPRs; w_t = exp(emis_t) staged into LDS.
// Linear domain (no exp/log in the recurrence); exact power-of-2 renorm
// every 4 steps.
//
// Round-5 change: the per-step broadcast is an LDS ROUND-TRIP, not 64
// v_readlane's. Rounds 2-4 were pinned at ~1078 cyc/step, VALUBusy 40%:
// v_readlane writes an SGPR and the dependent v_fma reads it — mandatory
// VALU->SGPR->VALU hazard wait states, serialized by SGPR-pool reuse
// (~650 cyc/step of stall). Now: ds_write_b32 state, then 16 ds_read_b128
// at wave-uniform addresses (HW broadcast, conflict-free) -> all-VGPR
// dataflow, pipelined DS reads, zero SGPR hazards. Renorm reference x[0]
// comes free as the first broadcast word (uniform) — no readlane there
// either. Single-wave LDS ordering -> no barriers in the loop.
__global__ __launch_bounds__(128) void crf_fwd_bwd(
    const float* __restrict__ emis,   // [B, T, L]
    const float* __restrict__ trans,  // [L, L]  trans[next, prev]
    float* __restrict__ out)          // [B]
{
    const int b    = blockIdx.x;
    const int tid  = threadIdx.x;
    const int lane = tid & 63;
    const int w    = tid >> 6;  // 0 = forward, 1 = backward

    // [wave][buf][CHUNK*NTAG] emission staging (exp'd), 32 KB total
    __shared__ float  lds[2 * 2 * CHUNK * NTAG];
    __shared__ float4 xb4[2][NTAG / 4];   // per-wave broadcast buffer (16B aligned)
    __shared__ float  sh[2][NTAG];

    const float L2E = 1.4426950408889634f;
    const float LN2 = 0.6931471805599453f;

    // Per-lane transition row, exponentiated, in 64 VGPRs.
    //   fwd: E[k] = exp(trans[lane, k])   (reduce over prev = k)
    //   bwd: E[k] = exp(trans[k, lane])   (reduce over next = k)
    // Masked entries (-10000) flush to exactly 0.
    float E[NTAG];
    if (w == 0) {
        const float4* rowp = (const float4*)(trans + lane * NTAG);
        #pragma unroll
        for (int k4 = 0; k4 < NTAG / 4; ++k4) {
            float4 v = rowp[k4];
            E[4 * k4 + 0] = exp2f(v.x * L2E);
            E[4 * k4 + 1] = exp2f(v.y * L2E);
            E[4 * k4 + 2] = exp2f(v.z * L2E);
            E[4 * k4 + 3] = exp2f(v.w * L2E);
        }
    } else {
        #pragma unroll
        for (int k = 0; k < NTAG; ++k)
            E[k] = exp2f(trans[k * NTAG + lane] * L2E);
    }

    const float* eb = emis + (size_t)b * TLEN * NTAG;
    float* xbuf = (float*)xb4[w];

    // chunk staging: 8 float4/lane covers CHUNK*NTAG floats per chunk
    float4 r0, r1, r2, r3, r4, r5, r6, r7;
    #define LOAD_CHUNK(baseT)                                        \
        do {                                                         \
            const float4* gp = (const float4*)(eb + (baseT) * NTAG); \
            r0 = gp[0 * 64 + lane]; r1 = gp[1 * 64 + lane];          \
            r2 = gp[2 * 64 + lane]; r3 = gp[3 * 64 + lane];          \
            r4 = gp[4 * 64 + lane]; r5 = gp[5 * 64 + lane];          \
            r6 = gp[6 * 64 + lane]; r7 = gp[7 * 64 + lane];          \
        } while (0)

    #define EXP4(v) make_float4(exp2f((v).x * L2E), exp2f((v).y * L2E), \
                                exp2f((v).z * L2E), exp2f((v).w * L2E))
    #define STORE_CHUNK_EXP(bufp)                                    \
        do {                                                         \
            float4* b4 = (float4*)(bufp);                            \
            b4[0 * 64 + lane] = EXP4(r0); b4[1 * 64 + lane] = EXP4(r1); \
            b4[2 * 64 + lane] = EXP4(r2); b4[3 * 64 + lane] = EXP4(r3); \
            b4[4 * 64 + lane] = EXP4(r4); b4[5 * 64 + lane] = EXP4(r5); \
            b4[6 * 64 + lane] = EXP4(r6); b4[7 * 64 + lane] = EXP4(r7); \
        } while (0)

    // Broadcast matvec: read the whole 64-float state via 16 b128 loads at
    // wave-uniform addresses (HW broadcast), then 64 fma into 8 accumulators.
    // xref := state[0], uniform across lanes (renorm reference, no readlane).
    #define BMATVEC(ssum, xref)                                      \
        do {                                                         \
            const float4* xq_ = (const float4*)xbuf;                 \
            float4 xv_[16];                                          \
            _Pragma("unroll")                                        \
            for (int j = 0; j < 16; ++j) xv_[j] = xq_[j];            \
            xref = xv_[0].x;                                         \
            float a0=0.f,a1=0.f,a2=0.f,a3=0.f;                       \
            float a4=0.f,a5=0.f,a6=0.f,a7=0.f;                       \
            _Pragma("unroll")                                        \
            for (int j = 0; j < 16; j += 2) {                        \
                a0 = fmaf(xv_[j].x,     E[4*j + 0], a0);             \
                a1 = fmaf(xv_[j].y,     E[4*j + 1], a1);             \
                a2 = fmaf(xv_[j].z,     E[4*j + 2], a2);             \
                a3 = fmaf(xv_[j].w,     E[4*j + 3], a3);             \
                a4 = fmaf(xv_[j + 1].x, E[4*j + 4], a4);             \
                a5 = fmaf(xv_[j + 1].y, E[4*j + 5], a5);             \
                a6 = fmaf(xv_[j + 1].z, E[4*j + 6], a6);             \
                a7 = fmaf(xv_[j + 1].w, E[4*j + 7], a7);             \
            }                                                        \
            ssum = ((a0 + a1) + (a2 + a3)) + ((a4 + a5) + (a6 + a7)); \
        } while (0)

    // exact power-of-2 renorm: xref is lane-uniform (from broadcast), one
    // step behind val — growth <= ~2^15/step keeps everything in range.
    #define RSCALE(xref, off, val)                                        \
        do {                                                              \
            int e_ = (int)((__float_as_uint(xref) >> 23) & 0xffu) - 127;  \
            off += e_;                                                    \
            val *= __uint_as_float((unsigned)(127 - e_) << 23);           \
        } while (0)

    float x;        // recursion state, one tag per lane
    int   off = 0;  // accumulated power-of-2 offset (exact)

    if (w == 0) {
        x = (lane == START_TAG) ? 1.0f : 0.0f;  // a_0 = exp(init)
        xbuf[lane] = x;                          // seed broadcast buffer

        LOAD_CHUNK(0);
        #pragma clang loop unroll(disable)
        for (int ci = 0; ci < 8; ++ci) {
            float* buf = &lds[(ci & 1) * (CHUNK * NTAG)];
            STORE_CHUNK_EXP(buf);
            if (ci < 7) LOAD_CHUNK((ci + 1) * CHUNK);  // in flight ~32 steps

            #pragma clang loop unroll(disable)
            for (int sg = 0; sg < 8; ++sg) {
                #pragma unroll
                for (int q = 0; q < 4; ++q) {
                    const int s = sg * 4 + q;
                    float em = buf[s * NTAG + lane];  // hidden under matvec
                    float ssum, xref;
                    BMATVEC(ssum, xref);
                    float xnew = ssum * em;
                    if (q == 3) RSCALE(xref, off, xnew);
                    xbuf[lane] = xnew;                // in-order DS: next
                    x = xnew;                         // step reads see it
                }
            }
        }
    } else {
        // y_511 seeded via first step: state starts as b_512 = exp(trans[STOP,:])
        x = exp2f(trans[STOP_TAG * NTAG + lane] * L2E);

        LOAD_CHUNK(HALF + 7 * CHUNK);
        #pragma clang loop unroll(disable)
        for (int i = 0; i < 8; ++i) {
            const int ci = 7 - i;                     // consume descending t
            float* buf = &lds[(2 + (i & 1)) * (CHUNK * NTAG)];
            STORE_CHUNK_EXP(buf);
            if (i < 7) LOAD_CHUNK(HALF + (ci - 1) * CHUNK);

            float wcur = buf[(CHUNK - 1) * NTAG + lane];  // prefetch (needed
            #pragma clang loop unroll(disable)            //  at step START)
            for (int sg = 0; sg < 8; ++sg) {
                #pragma unroll
                for (int q = 0; q < 4; ++q) {
                    const int s  = CHUNK - 1 - (sg * 4 + q);
                    const int sn = (s > 0) ? s - 1 : 0;
                    float wnext = buf[sn * NTAG + lane];
                    xbuf[lane] = x * wcur;            // u = w_t ∘ state
                    float ssum, xref;
                    BMATVEC(ssum, xref);
                    float xnew = ssum;                // b_t = E^T u
                    if (q == 3) RSCALE(xref, off, xnew);
                    x = xnew;
                    wcur = wnext;
                }
            }
        }
    }

    // back to log2 domain once, merge the two half-chains
    sh[w][lane] = log2f(x) + (float)off;   // -inf for masked tags, safe
    __syncthreads();

    if (w == 0) {
        float v = sh[0][lane] + sh[1][lane];
        float m = v;
        #pragma unroll
        for (int d = 1; d < 64; d <<= 1) m = fmaxf(m, __shfl_xor(m, d, 64));
        float e = exp2f(v - m);
        #pragma unroll
        for (int d = 1; d < 64; d <<= 1) e += __shfl_xor(e, d, 64);
        if (lane == 0) out[b] = LN2 * (m + log2f(e));
    }
}

extern "C" void kernel_launch(void* const* d_in, const int* in_sizes, int n_in,
                              void* d_out, int out_size, void* d_ws, size_t ws_size,
                              hipStream_t stream) {
    const float* emis  = (const float*)d_in[0];   // [512, 512, 64] f32
    const float* trans = (const float*)d_in[1];   // [64, 64] f32
    float* out = (float*)d_out;                   // [512] f32
    (void)in_sizes; (void)n_in; (void)out_size; (void)d_ws; (void)ws_size;
    crf_fwd_bwd<<<512, 128, 0, stream>>>(emis, trans, out);
}